// Round 6
// baseline (504.376 us; speedup 1.0000x reference)
//
#include <hip/hip_runtime.h>

// Problem shapes (fixed by setup_inputs)
namespace {
constexpr int B  = 8;
constexpr int N  = 100;
constexpr int C  = 256;
constexpr int H  = 160;
constexpr int W  = 160;
constexpr int NC = 80;      // NUM_CLASSES
constexpr int HH = 80;      // rows per half-plane block
constexpr int Q  = 40;      // float4 quads per row
constexpr int T1 = 512;     // 8 waves; 51.2KB LDS -> 3 blocks/CU staggered
}

// image_h / image_w arrive as 1-element arrays of unknown dtype (python
// scalar). Read as int32; if implausible, reinterpret the bits as float32.
__device__ inline float read_dim(const int* p) {
    int i = *p;
    if (i >= 1 && i <= (1 << 26)) return (float)i;
    return __int_as_float(i);
}

// Kernel 1: one block per (b, c, half). Stage half-plane in LDS, then each
// wave directly sums its boxes' pixels (4-row x 16-quad lane tiling, b128
// LDS reads, no scans / no divergent gathers / no hot-loop atomics), and
// global-atomically adds per-class partial means into zeroed `out`.
extern "C" __global__ void __launch_bounds__(T1, 6)
vpe_accum(const float* __restrict__ features,  // [B,C,H,W]
          const float* __restrict__ boxes,     // [B,N,4]
          const int*   __restrict__ gt,        // [B,N]
          const int*   __restrict__ imh_p,
          const int*   __restrict__ imw_p,
          float*       __restrict__ out)       // [B,NC,C], pre-zeroed
{
    __shared__ float4 Pl[HH * Q];      // 51,200 B half-plane
    __shared__ int    bxx[N];          // x1 | x2<<16
    __shared__ int    byy[N];          // y1r | y2r<<16 (half-relative)
    __shared__ int    bcls[N];         // class, or -1 invalid
    __shared__ float  bwgt[N];         // 1/area
    __shared__ float  cls_sum[NC];
    __shared__ int    cls_cnt[NC];

    const int tid  = threadIdx.x;
    const int wv   = tid >> 6, lane = tid & 63;
    const int rl   = lane >> 4, ql = lane & 15;
    const int bid  = blockIdx.x;
    const int b    = bid / (C * 2);
    const int rem  = bid - b * (C * 2);
    const int c    = rem >> 1;
    const int half = rem & 1;
    const int h0   = half * HH;

    if (tid < NC) { cls_sum[tid] = 0.f; cls_cnt[tid] = 0; }
    __syncthreads();

    // Box setup (uniform per b; recomputed per block — trivial cost).
    if (tid < N) {
        float imw = read_dim(imw_p), imh = read_dim(imh_p);
        float sx = (float)W / imw, sy = (float)H / imh;
        const float* bp = boxes + (size_t)(b * N + tid) * 4;
        int x1 = (int)fminf(fmaxf(floorf(bp[0] * sx), 0.f), (float)W);
        int y1 = (int)fminf(fmaxf(floorf(bp[1] * sy), 0.f), (float)H);
        int x2 = (int)fminf(fmaxf(floorf(bp[2] * sx), 0.f), (float)W);
        int y2 = (int)fminf(fmaxf(floorf(bp[3] * sy), 0.f), (float)H);
        bool valid = (x2 > x1) && (y2 > y1);
        int y1r = min(max(y1 - h0, 0), HH);
        int y2r = min(max(y2 - h0, 0), HH);
        bxx[tid] = x1 | (x2 << 16);
        byy[tid] = y1r | (y2r << 16);
        int cls = gt[b * N + tid];
        bcls[tid] = valid ? cls : -1;
        bwgt[tid] = 1.f / (float)max((x2 - x1) * (y2 - y1), 1);
        if (valid) atomicAdd(&cls_cnt[cls], 1);   // global count (not clipped)
    }

    // Stage half-plane: independent coalesced float4 loads -> LDS.
    {
        const float4* src4 = (const float4*)features
                           + ((size_t)(b * C + c) * H + h0) * Q;
        #pragma unroll
        for (int i = tid; i < HH * Q; i += T1) Pl[i] = src4[i];
    }
    __syncthreads();

    // Direct box sums. Wave wv owns boxes wv, wv+8, ... Lane tiling: 4 rows
    // (rl) x 16 quads (ql); uniform trip counts -> no divergent control flow.
    for (int n = wv; n < N; n += T1 / 64) {
        const int cls = bcls[n];
        if (cls < 0) continue;
        const int bx = bxx[n], by = byy[n];
        const int x1 = bx & 0xffff, x2 = bx >> 16;
        const int y1 = by & 0xffff, y2 = by >> 16;
        if (y1 >= y2) continue;                  // box not in this half
        const int q0 = x1 >> 2, q1 = (x2 + 3) >> 2;
        const int nrr = (y2 - y1 + 3) >> 2;
        const int nqq = (q1 - q0 + 15) >> 4;

        float acc = 0.f;
        for (int rr = 0; rr < nrr; ++rr) {
            const int r = y1 + rl + (rr << 2);
            const bool rok = (r < y2);
            for (int qq = 0; qq < nqq; ++qq) {
                const int q = q0 + ql + (qq << 4);
                if (rok && q < q1) {
                    float4 v = Pl[r * Q + q];
                    if (q == q0 || q == q1 - 1) {    // edge-quad masking
                        int xb = q << 2;
                        v.x = (xb     >= x1 && xb     < x2) ? v.x : 0.f;
                        v.y = (xb + 1 >= x1 && xb + 1 < x2) ? v.y : 0.f;
                        v.z = (xb + 2 >= x1 && xb + 2 < x2) ? v.z : 0.f;
                        v.w = (xb + 3 >= x1 && xb + 3 < x2) ? v.w : 0.f;
                    }
                    acc += (v.x + v.y) + (v.z + v.w);
                }
            }
        }
        #pragma unroll
        for (int d = 1; d < 64; d <<= 1) acc += __shfl_xor(acc, d, 64);
        if (lane == 0)
            atomicAdd(&cls_sum[cls], acc * bwgt[n] / (float)cls_cnt[cls]);
    }
    __syncthreads();

    // Combine the two halves via global f32 atomics (out pre-zeroed; 2 adds
    // per address total).
    if (tid < NC && cls_cnt[tid] > 0)
        atomicAdd(&out[((size_t)b * NC + tid) * C + c], cls_sum[tid]);
}

// Kernel 2: negative-pixel fallback for empty classes. One block per (b,cls).
extern "C" __global__ void __launch_bounds__(256)
vpe_finalize(const float* __restrict__ features,
             const float* __restrict__ boxes,
             const int*   __restrict__ gt,
             const int*   __restrict__ neg_y,
             const int*   __restrict__ neg_x,
             const int*   __restrict__ imh_p,
             const int*   __restrict__ imw_p,
             float*       __restrict__ out)
{
    __shared__ int cnt;
    const int tid = threadIdx.x;
    const int b   = blockIdx.x / NC;
    const int cls = blockIdx.x - b * NC;

    if (tid == 0) cnt = 0;
    __syncthreads();
    if (tid < N && gt[b * N + tid] == cls) {
        float imw = read_dim(imw_p), imh = read_dim(imh_p);
        float sx = (float)W / imw, sy = (float)H / imh;
        const float* bp = boxes + (size_t)(b * N + tid) * 4;
        int x1 = (int)fminf(fmaxf(floorf(bp[0] * sx), 0.f), (float)W);
        int y1 = (int)fminf(fmaxf(floorf(bp[1] * sy), 0.f), (float)H);
        int x2 = (int)fminf(fmaxf(floorf(bp[2] * sx), 0.f), (float)W);
        int y2 = (int)fminf(fmaxf(floorf(bp[3] * sy), 0.f), (float)H);
        if ((x2 > x1) && (y2 > y1)) atomicAdd(&cnt, 1);
    }
    __syncthreads();
    if (cnt == 0) {
        const int y = neg_y[b * NC + cls], x = neg_x[b * NC + cls];
        const int c = tid;   // 256 threads = 256 channels
        out[((size_t)b * NC + cls) * C + c] =
            features[((size_t)(b * C + c) * H + y) * W + x];
    }
}

extern "C" void kernel_launch(void* const* d_in, const int* in_sizes, int n_in,
                              void* d_out, int out_size, void* d_ws, size_t ws_size,
                              hipStream_t stream) {
    (void)in_sizes; (void)n_in; (void)d_ws; (void)ws_size;
    const float* features = (const float*)d_in[0];
    const float* boxes    = (const float*)d_in[1];
    const int*   gt       = (const int*)d_in[2];
    const int*   neg_y    = (const int*)d_in[3];
    const int*   neg_x    = (const int*)d_in[4];
    const int*   imh      = (const int*)d_in[5];
    const int*   imw      = (const int*)d_in[6];
    float*       out      = (float*)d_out;

    hipMemsetAsync(out, 0, (size_t)out_size * sizeof(float), stream);
    vpe_accum<<<dim3(B * C * 2), dim3(T1), 0, stream>>>(
        features, boxes, gt, imh, imw, out);
    vpe_finalize<<<dim3(B * NC), dim3(256), 0, stream>>>(
        features, boxes, gt, neg_y, neg_x, imh, imw, out);
}